// Round 9
// baseline (81.288 us; speedup 1.0000x reference)
//
#include <hip/hip_runtime.h>
#include <math.h>

// AWLoss closed-form: f = 24 - (0.5/511^2) * sum_c S1_c^2 / S2_c
// S1 = sum wgt*Re(F), S2 = sum wgt*|F|^2 over half-spectrum k1 in [0,511),
// k2 in [0,256), wgt = 1 for k2==0 else 2, F = conj(X)Y / |X|^2
// (1e-9 pre-whitening is < 1e-12 relative to |X|^2 ~ 1e4 -> dropped).
// X = DFT2(pad(target)), Y = DFT2(pad(recon)), pad offset 127.
//
// Round-9 structure (fixing R6-R8's grid starvation: 768 waves on 1024 SIMDs):
//  - stage2: 3072 wave-tasks (ch x k2-tile x kt-quarter). 8-wave blocks; each
//    block keeps its kt-quarter of the twiddle table LDS-RESIDENT (128 KiB,
//    filled once, zero barriers in the main loop). x1t frags register-pinned.
//    Per kt: 16 ds_read_b128 hidden under 64 MFMA.
//  - stage1: same shape: t-half twiddles LDS-resident, 8-wave blocks,
//    wave = 32 rows of one image, grid 256.

#define NCH 48
#define PADOFF 127
#define TWO_PI_F 6.283185307179586f

typedef float f32x4 __attribute__((ext_vector_type(4)));
typedef short s16x8 __attribute__((ext_vector_type(8)));
typedef unsigned short u16;

union frag_u { u16 u[8]; s16x8 v; };

__device__ __forceinline__ u16 f2bf(float f) {
    union { float f; unsigned u; } x; x.f = f;
    unsigned r = x.u + 0x7FFFu + ((x.u >> 16) & 1u);
    return (u16)(r >> 16);
}

#define MFMA16(A, B, C) __builtin_amdgcn_mfma_f32_16x16x32_bf16(A, B, C, 0, 0, 0)

// ---------------- setup: twiddle fragment table + acc zero ----------------
// w2f : fragments [kt(32)][c(2)][kk(8)][lane(64)][j(8)] bf16
//       element: tw((16kt + (l&15)) * (32kk + 8(l>>4) + j + 127) mod 511),
//       c=0 cos, c=1 sin; rows k1>=511 zeroed.
__global__ __launch_bounds__(256) void setup(u16* __restrict__ w2f,
                                             float* __restrict__ sacc) {
    __shared__ float cs[511], sn[511];
    int tid = threadIdx.x;
    for (int i = tid; i < 511; i += 256) {
        float a = -TWO_PI_F * (float)i / 511.0f;
        cs[i] = cosf(a);
        sn[i] = sinf(a);
    }
    __syncthreads();

    int i = blockIdx.x * 256 + tid;      // i < 262144
    int j = i & 7, l = (i >> 3) & 63, kk = (i >> 9) & 7;
    int c = (i >> 12) & 1, kt = i >> 13;
    int k1 = 16 * kt + (l & 15);
    u16 v = 0;
    if (k1 < 511) {
        int n = 32 * kk + 8 * (l >> 4) + j;
        int p = (k1 * (n + PADOFF)) % 511;
        v = f2bf(c ? sn[p] : cs[p]);
    }
    w2f[i] = v;
    if (blockIdx.x == 0 && tid < 2 * NCH) sacc[tid] = 0.0f;
}

// ---------------- LDS fill helper: 128 KiB, 512 threads ----------------
__device__ __forceinline__ void fill_tw(u16* tw, const u16* gp, int tid) {
    s16x8 tmp[16];
    #pragma unroll
    for (int i = 0; i < 16; ++i)
        tmp[i] = *(const s16x8*)(gp + (size_t)(tid + 512 * i) * 8);
    #pragma unroll
    for (int i = 0; i < 16; ++i)
        *(s16x8*)&tw[(size_t)(tid + 512 * i) * 8] = tmp[i];
}

// ---------------- stage 1: DFT along W (MFMA, LDS-resident twiddles) ----------------
// X1[n1][k2] = sum_b src[n1][b] * W[b][k2]; x1t[lc*4+tsel*2+c][k2][n1] bf16.
// grid = 256 blocks x 512 thr: th = bid&1 (t-half in LDS), task = (img, mp).
__global__ __launch_bounds__(512, 2) void stage1(const float* __restrict__ target,
                                                 const float* __restrict__ recon,
                                                 const u16* __restrict__ w2f,
                                                 u16* __restrict__ x1t,
                                                 int c0, int cc) {
    int tid = threadIdx.x;
    int w = tid >> 6, l = tid & 63;
    int lm = l & 15, lh = l >> 4;
    int th = blockIdx.x & 1;
    int bidh = blockIdx.x >> 1;          // 0..127

    __shared__ u16 tw[65536];            // 128 KiB: 8 t-tiles [tt][c][kk][l][8]
    fill_tw(tw, w2f + (size_t)th * 65536, tid);
    __syncthreads();

    int ntasks = 16 * cc;                // (img = 2cc) x (mp = 8)
    int task = bidh * 8 + w;             // stride 1024 >= ntasks: single pass
    if (task >= ntasks) return;
    int img = task >> 3;
    int mp  = task & 7;
    int lc = img >> 1;
    int tsel = img & 1;
    const float* src = (tsel == 0 ? target : recon) + (size_t)(c0 + lc) * 65536;

    // A fragments: 32 rows (2 sub-tiles of 16), full K=256, f32 -> bf16
    frag_u af[2][8];
    #pragma unroll
    for (int a = 0; a < 2; ++a) {
        const float* ap = src + (size_t)(32 * mp + 16 * a + lm) * 256 + 8 * lh;
        #pragma unroll
        for (int kk = 0; kk < 8; ++kk) {
            float4 v0 = *(const float4*)(ap + 32 * kk);
            float4 v1 = *(const float4*)(ap + 32 * kk + 4);
            af[a][kk].u[0] = f2bf(v0.x); af[a][kk].u[1] = f2bf(v0.y);
            af[a][kk].u[2] = f2bf(v0.z); af[a][kk].u[3] = f2bf(v0.w);
            af[a][kk].u[4] = f2bf(v1.x); af[a][kk].u[5] = f2bf(v1.y);
            af[a][kk].u[6] = f2bf(v1.z); af[a][kk].u[7] = f2bf(v1.w);
        }
    }
    #pragma unroll
    for (int a = 0; a < 2; ++a)
        #pragma unroll
        for (int kk = 0; kk < 8; ++kk)
            asm volatile("" : "+v"(af[a][kk].v));

    u16* chdst = x1t + (size_t)(lc * 4 + tsel * 2) * 65536;

    for (int tt = 0; tt < 8; ++tt) {
        int t = 8 * th + tt;
        f32x4 ac0 = {0,0,0,0}, as0 = {0,0,0,0}, ac1 = {0,0,0,0}, as1 = {0,0,0,0};
        #pragma unroll
        for (int kk = 0; kk < 8; ++kk) {
            s16x8 bc = *(const s16x8*)&tw[tt * 8192 + kk * 512 + l * 8];
            s16x8 bs = *(const s16x8*)&tw[tt * 8192 + 4096 + kk * 512 + l * 8];
            ac0 = MFMA16(af[0][kk].v, bc, ac0);
            as0 = MFMA16(af[0][kk].v, bs, as0);
            ac1 = MFMA16(af[1][kk].v, bc, ac1);
            as1 = MFMA16(af[1][kk].v, bs, as1);
        }
        // D element (m = 4lh+r, n = lm): n1 = 32mp+16a+4lh+r, k2 = 16t+lm
        ushort4 o0, o1;
        o0.x = f2bf(ac0[0]); o0.y = f2bf(ac0[1]);
        o0.z = f2bf(ac0[2]); o0.w = f2bf(ac0[3]);
        o1.x = f2bf(as0[0]); o1.y = f2bf(as0[1]);
        o1.z = f2bf(as0[2]); o1.w = f2bf(as0[3]);
        size_t off = (size_t)(16 * t + lm) * 256 + 32 * mp + 4 * lh;
        *(ushort4*)(chdst + off)         = o0;
        *(ushort4*)(chdst + 65536 + off) = o1;
        o0.x = f2bf(ac1[0]); o0.y = f2bf(ac1[1]);
        o0.z = f2bf(ac1[2]); o0.w = f2bf(ac1[3]);
        o1.x = f2bf(as1[0]); o1.y = f2bf(as1[1]);
        o1.z = f2bf(as1[2]); o1.w = f2bf(as1[3]);
        *(ushort4*)(chdst + off + 16)         = o0;
        *(ushort4*)(chdst + 65536 + off + 16) = o1;
    }
}

// ---------------- stage 2: DFT along H (MFMA, LDS-resident twiddles) + reduce ----------------
// grid = 256 blocks x 512 thr: ktq = bid&3 (8 kt tiles in LDS), wave-task =
// (lc, t); loop task stride 512. x1t frags register-pinned per task.
__global__ __launch_bounds__(512, 2) void stage2(const u16* __restrict__ x1t,
                                                 const u16* __restrict__ w2f,
                                                 float* __restrict__ sacc,
                                                 int c0, int cc) {
    int tid = threadIdx.x;
    int w = tid >> 6, l = tid & 63;
    int lm = l & 15, lh = l >> 4;
    int ktq = blockIdx.x & 3;
    int bidq = blockIdx.x >> 2;          // 0..63

    __shared__ u16 tw[65536];            // 128 KiB: 8 kt-tiles [i8][c][kk][l][8]
    fill_tw(tw, w2f + (size_t)ktq * 65536, tid);
    __syncthreads();

    int ntasks = 16 * cc;
    for (int task = bidq * 8 + w; task < ntasks; task += 512) {
        int lc = task >> 4;
        int t  = task & 15;

        const u16* base = x1t + (size_t)(4 * lc) * 65536;   // planes Xr,Xi,Yr,Yi
        size_t roff = (size_t)(16 * t + lm) * 256 + 8 * lh;

        s16x8 ar[8], ai[8], br[8], bi[8];
        #pragma unroll
        for (int kk = 0; kk < 8; ++kk) {
            size_t off = roff + 32 * kk;
            ar[kk] = *(const s16x8*)(base + off);
            ai[kk] = *(const s16x8*)(base + 65536 + off);
            br[kk] = *(const s16x8*)(base + 131072 + off);
            bi[kk] = *(const s16x8*)(base + 196608 + off);
        }
        #pragma unroll
        for (int kk = 0; kk < 8; ++kk)
            asm volatile("" : "+v"(ar[kk]), "+v"(ai[kk]), "+v"(br[kk]), "+v"(bi[kk]));

        int k2 = 16 * t + lm;
        float wgt = (k2 == 0) ? 1.f : 2.f;
        float s1 = 0.f, s2 = 0.f;

        for (int i8 = 0; i8 < 8; ++i8) {
            int kt = 8 * ktq + i8;
            f32x4 crr = {0,0,0,0}, cii = {0,0,0,0}, cri = {0,0,0,0}, cir = {0,0,0,0};
            f32x4 drr = {0,0,0,0}, dii = {0,0,0,0}, dri = {0,0,0,0}, dir = {0,0,0,0};
            #pragma unroll
            for (int kk = 0; kk < 8; ++kk) {
                s16x8 wr = *(const s16x8*)&tw[i8 * 8192 + kk * 512 + l * 8];
                s16x8 wi = *(const s16x8*)&tw[i8 * 8192 + 4096 + kk * 512 + l * 8];
                crr = MFMA16(wr, ar[kk], crr);
                cii = MFMA16(wi, ai[kk], cii);
                cri = MFMA16(wr, ai[kk], cri);
                cir = MFMA16(wi, ar[kk], cir);
                drr = MFMA16(wr, br[kk], drr);
                dii = MFMA16(wi, bi[kk], dii);
                dri = MFMA16(wr, bi[kk], dri);
                dir = MFMA16(wi, br[kk], dir);
            }
            #pragma unroll
            for (int r = 0; r < 4; ++r) {
                int k1 = 16 * kt + 4 * lh + r;
                float wg2 = (k1 < 511) ? wgt : 0.f;
                float Xr = crr[r] - cii[r], Xi = cri[r] + cir[r];
                float Yr = drr[r] - dii[r], Yi = dri[r] + dir[r];
                float Pr = Xr * Yr + Xi * Yi;
                float Pi = Xr * Yi - Xi * Yr;
                float Q  = Xr * Xr + Xi * Xi;
                float inv = 1.0f / (Q * Q + 1e-30f);
                s1 += wg2 * Pr * Q * inv;
                s2 += wg2 * (Pr * Pr + Pi * Pi) * inv;
            }
        }

        #pragma unroll
        for (int off = 32; off > 0; off >>= 1) {
            s1 += __shfl_down(s1, off);
            s2 += __shfl_down(s2, off);
        }
        if (l == 0) {
            atomicAdd(&sacc[c0 + lc], s1);
            atomicAdd(&sacc[NCH + c0 + lc], s2);
        }
    }
}

__global__ void finalize(const float* __restrict__ s, float* __restrict__ out) {
    int t = threadIdx.x;
    float v = 0.f;
    if (t < NCH) {
        float s1 = s[t], s2 = s[NCH + t];
        v = (s2 != 0.f) ? (s1 * s1) / s2 : 0.f;
    }
    for (int off = 32; off > 0; off >>= 1) v += __shfl_down(v, off);
    if (t == 0) out[0] = 24.0f - 0.5f * v / 261121.0f;
}

// ---------------- launch ----------------
extern "C" void kernel_launch(void* const* d_in, const int* in_sizes, int n_in,
                              void* d_out, int out_size, void* d_ws, size_t ws_size,
                              hipStream_t stream) {
    const float* recon  = (const float*)d_in[0];
    const float* target = (const float*)d_in[1];
    float* out = (float*)d_out;
    char* ws = (char*)d_ws;

    const size_t OFF_W2F = 0;                        // 524288 B
    const size_t OFF_S   = OFF_W2F + 524288;         // 512 B
    const size_t OFF_X1  = OFF_S + 512;

    u16*   w2f  = (u16*)(ws + OFF_W2F);
    float* sacc = (float*)(ws + OFF_S);
    u16*   x1t  = (u16*)(ws + OFF_X1);

    const size_t perch = 4ull * 65536 * 2;           // 512 KiB per channel
    size_t avail = (ws_size > OFF_X1) ? ws_size - OFF_X1 : 0;
    int chunk = (int)(avail / perch);
    if (chunk > NCH) chunk = NCH;
    if (chunk < 1) chunk = 1;

    setup<<<dim3(1024), dim3(256), 0, stream>>>(w2f, sacc);

    for (int c0 = 0; c0 < NCH; c0 += chunk) {
        int cc = (NCH - c0 < chunk) ? (NCH - c0) : chunk;
        stage1<<<dim3(256), dim3(512), 0, stream>>>(target, recon, w2f, x1t, c0, cc);
        stage2<<<dim3(256), dim3(512), 0, stream>>>(x1t, w2f, sacc, c0, cc);
    }
    finalize<<<dim3(1), dim3(64), 0, stream>>>(sacc, out);
}